// Round 17
// baseline (112.748 us; speedup 1.0000x reference)
//
#include <hip/hip_runtime.h>
#include <hip/hip_fp16.h>
#include <math.h>

#define S 256
#define A 180
#define B 4
#define RS 133            // row stride in dwords (odd -> bank spread)
#define NRW 73            // staged rows per strip: 64 + 2*4 margin + 1
#define ARR (NRW * RS)    // 9709 dwords per array; X + Y = 19418 dw = 77,672 B

typedef __fp16 h2 __attribute__((ext_vector_type(2)));   // matches cvt_pkrtz/fdot2

#if defined(__has_builtin)
#if __has_builtin(__builtin_amdgcn_fdot2)
#define USE_DOT2 1
#endif
#endif

// Kernel 1: inscribed-circle mask + fp32->fp16, and zero the output sinogram.
__global__ void radon_mask_f16(const float* __restrict__ in, __half* __restrict__ out,
                               float* __restrict__ osino) {
    int idx = blockIdx.x * 256 + threadIdx.x;    // 0 .. B*S*S-1
    int p = idx & (S * S - 1);
    int y = p >> 8;
    int x = p & 255;
    int dx = x - 128, dy = y - 128;
    float v = in[idx];
    v = (dx * dx + dy * dy <= 16384) ? v : 0.0f;
    out[idx] = __float2half(v);
    if (idx < A * B * S) osino[idx] = 0.0f;
}

// Kernel 2: grid (A,B,4). Block (a,b,h) owns taps with floor(py) in y-strip
// [64h, 64h+64) (py monotone in i; sn<0 at a=179 flips interval direction).
// LDS: parity-duplicated pair layout. X[r][k]=(v[2k],v[2k+1]),
// Y[r][k]=(v[2k+1],v[2k+2]) -> the (x0,x0+1) corner pair of each row is ONE
// aligned dword (array chosen by x0&1); two rows = ds_read2_b32. Values dot
// packed f16 weights via v_dot2_f32_f16 (no per-tap cvts). Borders zeroed by
// construction; ownership intervals have +/-4-row staged margins.
__global__ __launch_bounds__(1024, 8) void radon_lds_kernel(const __half* __restrict__ img,
                                                            float* __restrict__ out) {
    __shared__ uint lds_u[2 * ARR];              // 77,672 B -> 2 blocks/CU

    const int a = blockIdx.x;   // angle
    const int b = blockIdx.y;   // batch
    const int h = blockIdx.z;   // y-strip
    const int tid = threadIdx.x;
    const int ystart = 64 * h - 4;               // image row in LDS row 0

    float ang = (float)a * (float)(M_PI / 179.0);
    float sn, cs;
    sincosf(ang, &sn, &cs);

    // ---- stage strip: X = pair dwords, Y = shifted pairs; zeros outside ----
    {
        const uint* __restrict__ src = (const uint*)(img + (size_t)b * (S * S));
#pragma unroll
        for (int it = 0; it < 10; ++it) {
            int p = it * 1024 + tid;
            if (p < NRW * 131) {
                int r = p / 131;
                int ko = p - r * 131;            // 0..130
                int kk = ko - 2;                 // dword index -2..128
                int g = ystart + r;
                bool gv = ((unsigned)g < 256u);
                uint d0 = (gv && (unsigned)kk < 128u) ? src[g * 128 + kk] : 0u;
                uint d1 = (gv && (unsigned)(kk + 1) < 128u) ? src[g * 128 + kk + 1] : 0u;
                lds_u[r * RS + ko] = d0;                            // X
                lds_u[ARR + r * RS + ko] = (d0 >> 16) | (d1 << 16); // Y
            }
        }
    }
    __syncthreads();

    const int j = tid >> 2;      // ray index: 16 consecutive j per wave
    const int q = tid & 3;       // ray segment (lane-minor)

    const float ry = (float)j - 127.5f;
    const float bx = fmaf(-sn, ry, 127.5f);
    const float by = fmaf(cs, ry, 127.5f);
    const float ry2 = ry * ry;

    // disk trim (taps beyond d^2>16934 ~130.13^2 are provably zero)
    float hd = sqrtf(16934.0f - ry2);
    int ilo = max((int)ceilf(127.5f - hd), 0);
    int ihi = min((int)floorf(127.5f + hd) + 1, S);

    // strip ownership: py(i) crosses c at i = 127.5 + (c-by)/sn.
    // sn>=0: own [F(64h), F(64h+64)); sn<0 (a=179): direction flips.
    float invsn = 1.0f / sn;
    bool neg = (sn < 0.0f);
    float cLo = neg ? (float)(64 * h + 64) : (float)(64 * h);
    float cHi = neg ? (float)(64 * h) : (float)(64 * h + 64);
    float tLo = 127.5f + (cLo - by) * invsn;
    float tHi = 127.5f + (cHi - by) * invsn;
    int FLo = (int)fminf(fmaxf(ceilf(tLo), 0.0f), 256.0f);  // NaN -> 0
    int FHi = (int)fminf(fmaxf(ceilf(tHi), 0.0f), 256.0f);
    bool openLo = (h == (neg ? 3 : 0));
    bool openHi = (h == (neg ? 0 : 3));
    int lo0 = openLo ? ilo : max(ilo, FLo);
    int hi0 = openHi ? ihi : min(ihi, FHi);
    int len = max(hi0 - lo0, 0);
    int lo = lo0 + ((q * len) >> 2);
    int hi = lo0 + (((q + 1) * len) >> 2);

    // fold constants: px = cs*i + bxp ; local py = sn*i + byl
    const float bxp = fmaf(-127.5f, cs, bx);
    const float byl = fmaf(-127.5f, sn, by) - (float)ystart;

    float acc0 = 0.0f, acc1 = 0.0f;

#pragma unroll 4
    for (int i = lo; i < hi; ++i) {
        float fi = (float)i;
        float px = fmaf(cs, fi, bxp);
        float py = fmaf(sn, fi, byl);          // local: always > 0

        float x0f = floorf(px);
        float y0f = floorf(py);
        float wx = px - x0f;
        float wy = py - y0f;
        int x0 = (int)x0f;                     // may be negative: cast exact after floor
        int yl = (int)y0f;                     // local row, >= 0
        int k = x0 >> 1;                       // arithmetic shift = floor div
        int par = x0 & 1;
        int addr = yl * RS + (k + 2) + par * ARR;

        uint d0 = lds_u[addr];                 // (v(x0), v(x0+1)) of row y0
        uint d1 = lds_u[addr + RS];            // same pair of row y0+1

        float ux = 1.0f - wx;
        float uy = 1.0f - wy;
#ifdef USE_DOT2
        h2 w0 = __builtin_amdgcn_cvt_pkrtz(ux * uy, wx * uy);
        h2 w1 = __builtin_amdgcn_cvt_pkrtz(ux * wy, wx * wy);
        acc0 = __builtin_amdgcn_fdot2(__builtin_bit_cast(h2, d0), w0, acc0, false);
        acc1 = __builtin_amdgcn_fdot2(__builtin_bit_cast(h2, d1), w1, acc1, false);
#else
        float v00 = __half2float(__ushort_as_half((unsigned short)(d0 & 0xffffu)));
        float v10 = __half2float(__ushort_as_half((unsigned short)(d0 >> 16)));
        float v01 = __half2float(__ushort_as_half((unsigned short)(d1 & 0xffffu)));
        float v11 = __half2float(__ushort_as_half((unsigned short)(d1 >> 16)));
        acc0 = fmaf(ux * uy, v00, fmaf(wx * uy, v10, acc0));
        acc1 = fmaf(ux * wy, v01, fmaf(wx * wy, v11, acc1));
#endif
    }

    float acc = acc0 + acc1;

    // ---- reduce the 4 segments per j, then 4-way atomic combine ----
    __syncthreads();
    float* red = (float*)lds_u;
    red[tid] = acc;
    __syncthreads();
    if (tid < 256) {
        float4 v = ((const float4*)red)[tid];
        atomicAdd(&out[((size_t)b * A + a) * S + tid], v.x + v.y + v.z + v.w);
    }
}

extern "C" void kernel_launch(void* const* d_in, const int* in_sizes, int n_in,
                              void* d_out, int out_size, void* d_ws, size_t ws_size,
                              hipStream_t stream) {
    const float* x = (const float*)d_in[0];
    float* out = (float*)d_out;
    __half* masked = (__half*)d_ws;  // B*S*S halves = 512 KiB

    radon_mask_f16<<<dim3((B * S * S) / 256), dim3(256), 0, stream>>>(x, masked, out);
    radon_lds_kernel<<<dim3(A, B, 4), dim3(1024), 0, stream>>>(masked, out);
}

// Round 18
// 101.780 us; speedup vs baseline: 1.1078x; 1.1078x over previous
//
#include <hip/hip_runtime.h>
#include <hip/hip_fp16.h>
#include <math.h>

#define S 256
#define A 180
#define B 4
#define RSW 265           // row stride in dwords (odd -> bank spread); 1 dword = 1 pixel-pair
#define NRW 37            // staged rows: 32 owned + 2 margin below + 3 above (y1)
#define LDSW (NRW * RSW)  // 9805 dwords = 39,220 B -> 4 blocks/CU (32 waves)

// Kernel 1: circle mask + pack batch-pairs: ws[c*65536 + p] = f16(b=2c) | f16(b=2c+1)<<16.
// Also zeroes the output sinogram (grid covers 184,320 threads).
__global__ void radon_mask_pack(const float* __restrict__ in, uint* __restrict__ ws,
                                float* __restrict__ osino) {
    int idx = blockIdx.x * 256 + threadIdx.x;    // 0 .. 184319
    if (idx < 2 * S * S) {
        int c = idx >> 16;          // batch pair 0/1
        int p = idx & 65535;
        int y = p >> 8;
        int x = p & 255;
        int dx = x - 128, dy = y - 128;
        bool inside = (dx * dx + dy * dy <= 16384);
        float v0 = in[(2 * c) * (S * S) + p];
        float v1 = in[(2 * c + 1) * (S * S) + p];
        v0 = inside ? v0 : 0.0f;
        v1 = inside ? v1 : 0.0f;
        uint lo = (uint)__half_as_ushort(__float2half(v0));
        uint hi = (uint)__half_as_ushort(__float2half(v1));
        ws[c * (S * S) + p] = lo | (hi << 16);
    }
    if (idx < A * B * S) osino[idx] = 0.0f;
}

// Kernel 2: grid (A, 2 batch-pairs, 8 y-strips), 512 threads = (j=tid>>1, q=tid&1).
// Block (a,c,h) owns taps with floor(py) in [32h, 32h+32) (py monotone in i;
// sn<0 at a=179 flips the interval direction -- R17-verified logic). Strip
// staged rows 32h-2 .. 32h+34 with zero borders; pixel-pair layout means each
// corner dword serves BOTH batches of the pair: 4 ds_read_b32 (-> 2
// ds_read2_b32) per 2 batch-taps, and address/weight VALU amortized 2x.
__global__ __launch_bounds__(512, 8) void radon_lds_kernel(const uint* __restrict__ ws,
                                                           float* __restrict__ out) {
    __shared__ uint lds[LDSW];

    const int a = blockIdx.x;   // angle
    const int c = blockIdx.y;   // batch pair
    const int h = blockIdx.z;   // y-strip
    const int tid = threadIdx.x;
    const int ystart = 32 * h - 2;               // image row held in LDS row 0

    float ang = (float)a * (float)(M_PI / 179.0);
    float sn, cs;
    sincosf(ang, &sn, &cs);

    // ---- stage strip (zeros outside image/margins) ----
    {
        const uint* __restrict__ src = ws + c * (S * S);
#pragma unroll
        for (int it = 0; it < 20; ++it) {
            int p = it * 512 + tid;
            if (p < LDSW) {
                int r = p / RSW;
                int lx = p - r * RSW;            // 0..264
                int x = lx - 4;                  // image x
                int g = ystart + r;              // image y
                uint d = 0u;
                if (((unsigned)g < 256u) && ((unsigned)x < 256u)) d = src[g * 256 + x];
                lds[p] = d;
            }
        }
    }
    __syncthreads();

    const int j = tid >> 1;      // ray index
    const int q = tid & 1;       // ray segment (lane-minor)

    const float ry = (float)j - 127.5f;
    const float bx = fmaf(-sn, ry, 127.5f);
    const float by = fmaf(cs, ry, 127.5f);
    const float ry2 = ry * ry;

    // disk trim (taps beyond d^2>16934 ~130.13^2 are provably zero)
    float hd = sqrtf(16934.0f - ry2);
    int ilo = max((int)ceilf(127.5f - hd), 0);
    int ihi = min((int)floorf(127.5f + hd) + 1, S);

    // strip ownership: py(i) crosses level c at i = 127.5 + (c-by)/sn.
    float invsn = 1.0f / sn;
    bool neg = (sn < 0.0f);
    float cLo = neg ? (float)(32 * h + 32) : (float)(32 * h);
    float cHi = neg ? (float)(32 * h) : (float)(32 * h + 32);
    float tLo = 127.5f + (cLo - by) * invsn;
    float tHi = 127.5f + (cHi - by) * invsn;
    int FLo = (int)fminf(fmaxf(ceilf(tLo), 0.0f), 256.0f);  // NaN -> 0
    int FHi = (int)fminf(fmaxf(ceilf(tHi), 0.0f), 256.0f);
    bool openLo = (h == (neg ? 7 : 0));
    bool openHi = (h == (neg ? 0 : 7));
    int lo0 = openLo ? ilo : max(ilo, FLo);
    int hi0 = openHi ? ihi : min(ihi, FHi);
    int len = max(hi0 - lo0, 0);
    int lo = lo0 + ((q * len) >> 1);
    int hi = lo0 + (((q + 1) * len) >> 1);

    // folded constants: px_l = cs*i + bxp (includes +4 col offset);
    // py_l = sn*i + byl (local rows: includes -ystart)
    const float bxp = fmaf(-127.5f, cs, bx) + 4.0f;
    const float byl = fmaf(-127.5f, sn, by) - (float)ystart;

    float accA = 0.0f, accB = 0.0f;

#pragma unroll 4
    for (int i = lo; i < hi; ++i) {
        float fi = (float)i;
        float px = fmaf(cs, fi, bxp);
        float py = fmaf(sn, fi, byl);

        float x0f = floorf(px);
        float y0f = floorf(py);
        float wx = px - x0f;
        float wy = py - y0f;
        int xl = (int)x0f;                     // LDS col of x0 (>=1)
        int yl = (int)y0f;                     // LDS row of y0 (>=1)
        int addr = yl * RSW + xl;

        uint d00 = lds[addr];
        uint d10 = lds[addr + 1];
        uint d01 = lds[addr + RSW];
        uint d11 = lds[addr + RSW + 1];

        float ux = 1.0f - wx;
        float uy = 1.0f - wy;
        float w00 = ux * uy;
        float w10 = wx * uy;
        float w01 = ux * wy;
        float w11 = wx * wy;

        accA = fmaf(w00, __half2float(__ushort_as_half((unsigned short)(d00 & 0xffffu))),
               fmaf(w10, __half2float(__ushort_as_half((unsigned short)(d10 & 0xffffu))),
               fmaf(w01, __half2float(__ushort_as_half((unsigned short)(d01 & 0xffffu))),
               fmaf(w11, __half2float(__ushort_as_half((unsigned short)(d11 & 0xffffu))), accA))));
        accB = fmaf(w00, __half2float(__ushort_as_half((unsigned short)(d00 >> 16))),
               fmaf(w10, __half2float(__ushort_as_half((unsigned short)(d10 >> 16))),
               fmaf(w01, __half2float(__ushort_as_half((unsigned short)(d01 >> 16))),
               fmaf(w11, __half2float(__ushort_as_half((unsigned short)(d11 >> 16))), accB))));
    }

    // ---- reduce 2 segments per j, then atomic combine (8 strips deep) ----
    __syncthreads();
    float2* red = (float2*)lds;
    red[tid] = make_float2(accA, accB);
    __syncthreads();
    if (tid < 256) {
        float2 v0 = red[2 * tid];
        float2 v1 = red[2 * tid + 1];
        size_t o = ((size_t)(2 * c) * A + a) * S + tid;
        atomicAdd(&out[o], v0.x + v1.x);
        atomicAdd(&out[o + (size_t)A * S], v0.y + v1.y);
    }
}

extern "C" void kernel_launch(void* const* d_in, const int* in_sizes, int n_in,
                              void* d_out, int out_size, void* d_ws, size_t ws_size,
                              hipStream_t stream) {
    const float* x = (const float*)d_in[0];
    float* out = (float*)d_out;
    uint* ws = (uint*)d_ws;  // 2 * 65536 dwords = 512 KiB

    radon_mask_pack<<<dim3(720), dim3(256), 0, stream>>>(x, ws, out);
    radon_lds_kernel<<<dim3(A, 2, 8), dim3(512), 0, stream>>>(ws, out);
}